// Round 2
// baseline (1738.899 us; speedup 1.0000x reference)
//
#include <hip/hip_runtime.h>
#include <hip/hip_bf16.h>

// ---------------- types / helpers ----------------
typedef __attribute__((ext_vector_type(8))) short   vshort8;   // 8 x bf16 bits (4 VGPRs)
typedef __attribute__((ext_vector_type(8))) unsigned short vushort8;
typedef __attribute__((ext_vector_type(4))) float   vfloat4;
typedef __attribute__((ext_vector_type(2))) float   vfloat2;

__device__ __forceinline__ float bf2f(unsigned short h) {
    union { unsigned u; float f; } x; x.u = ((unsigned)h) << 16; return x.f;
}
__device__ __forceinline__ unsigned short f2bf(float f) {
    union { float f; unsigned u; } x; x.f = f;
    unsigned r = x.u + 0x7fffu + ((x.u >> 16) & 1u);
    return (unsigned short)(r >> 16);
}
__device__ __forceinline__ void cp16_async(const void* g, void* l) {
    __builtin_amdgcn_global_load_lds(
        (const __attribute__((address_space(1))) unsigned int*)g,
        (__attribute__((address_space(3))) unsigned int*)l, 16, 0, 0);
}

// ---------------- constants ----------------
#define Bc 4
#define Tc 2048
#define Dc 2048
#define Hc 32
#define KHc 64
#define BTc (Bc*Tc)              // 8192
#define BTDc ((size_t)BTc*Dc)    // 16,777,216

// ---------------- GEMM: C[M,N] = A[M,K] @ BT[N,K]^T  (bf16 in, f32 acc) ----------------
// 128x128 tile, BK=32, 4 waves (2x2 of 64x64), mfma_f32_16x16x32_bf16.
struct EpiP {
    float* of;                 // f32 out
    unsigned short* ob;        // bf16 out
    const float* a0;           // aux f32 (x / decay)
    const float* a1;           // aux f32 (shift_state_in)
    const unsigned short* ab;  // aux bf16 (v2 partial)
    const float* vec;          // per-col vector (time_maa_*, time_decay)
};

template<int EPI>
__global__ __launch_bounds__(256) void gemm_bt(
    const unsigned short* __restrict__ A, int lda,
    const unsigned short* __restrict__ BT, int ldbt,
    int M, int N, int K, EpiP ep)
{
    __shared__ unsigned short lA[128 * 32];
    __shared__ unsigned short lB[128 * 32];
    const int tid  = threadIdx.x;
    const int lane = tid & 63;
    const int w    = tid >> 6;
    const int mt   = blockIdx.y, nt = blockIdx.x;
    const int wm = (w >> 1) * 64, wn = (w & 1) * 64;
    const int frow = lane & 15, fk = (lane >> 4) * 8;

    vfloat4 acc[4][4];
#pragma unroll
    for (int i = 0; i < 4; i++)
#pragma unroll
        for (int j = 0; j < 4; j++) acc[i][j] = vfloat4{0.f, 0.f, 0.f, 0.f};

    for (int k0 = 0; k0 < K; k0 += 32) {
        __syncthreads();
#pragma unroll
        for (int p = 0; p < 2; p++) {
            int idx = p * 256 + tid;
            int row = idx >> 2, colh = (idx & 3) * 8;
            cp16_async(A + (size_t)(mt * 128 + row) * lda + k0 + colh, &lA[idx * 8]);
        }
#pragma unroll
        for (int p = 0; p < 2; p++) {
            int idx = p * 256 + tid;
            int row = idx >> 2, colh = (idx & 3) * 8;
            cp16_async(BT + (size_t)(nt * 128 + row) * ldbt + k0 + colh, &lB[idx * 8]);
        }
        __syncthreads();

        vshort8 af[4], bfr[4];
#pragma unroll
        for (int m = 0; m < 4; m++) af[m]  = *(const vshort8*)&lA[(wm + m * 16 + frow) * 32 + fk];
#pragma unroll
        for (int n = 0; n < 4; n++) bfr[n] = *(const vshort8*)&lB[(wn + n * 16 + frow) * 32 + fk];
#pragma unroll
        for (int m = 0; m < 4; m++)
#pragma unroll
            for (int n = 0; n < 4; n++)
                acc[m][n] = __builtin_amdgcn_mfma_f32_16x16x32_bf16(af[m], bfr[n], acc[m][n], 0, 0, 0);
    }

    const int crow0 = mt * 128 + wm, ccol0 = nt * 128 + wn;
#pragma unroll
    for (int m = 0; m < 4; m++) {
#pragma unroll
        for (int n = 0; n < 4; n++) {
            int col = ccol0 + n * 16 + (lane & 15);
            if (col >= N) continue;
#pragma unroll
            for (int q = 0; q < 4; q++) {
                int row = crow0 + m * 16 + (lane >> 4) * 4 + q;
                float a = acc[m][n][q];
                size_t o = (size_t)row * N + col;
                if (EPI == 0) {                       // plain f32 store
                    ep.of[o] = a;
                } else if (EPI == 1) {                // plain bf16 store
                    ep.ob[o] = f2bf(a);
                } else if (EPI == 2) {                // tanh -> bf16
                    ep.ob[o] = f2bf(tanhf(a));
                } else if (EPI == 3) {                // MIX: x + (xprev-x)*(vec[col]+acc)
                    float xv = ep.a0[o];
                    int t = row & (Tc - 1);
                    float xp = t ? ep.a0[o - Dc] : ep.a1[(size_t)(row >> 11) * Dc + col];
                    ep.ob[o] = f2bf(xv + (xp - xv) * (ep.vec[col] + a));
                } else if (EPI == 4) {                // KD: acc * (1 - decay)
                    ep.ob[o] = f2bf(a * (1.f - ep.a0[o]));
                } else if (EPI == 5) {                // DECAY: exp(-exp(vec[col]+acc)) f32
                    ep.of[o] = expf(-expf(ep.vec[col] + a));
                } else if (EPI == 6) {                // ADDB: acc + bf16 aux -> bf16 (in-place ok)
                    ep.ob[o] = f2bf(a + bf2f(ep.ab[o]));
                }
            }
        }
    }
}

// ---------------- prep: xxx = x + (xprev-x)*time_maa_x  -> bf16 ----------------
__global__ __launch_bounds__(256) void prep_xxx(
    const float* __restrict__ x, const float* __restrict__ shift_in,
    const float* __restrict__ tmx, unsigned short* __restrict__ xxx)
{
    int row = blockIdx.x, tid = threadIdx.x;
    int t = row & (Tc - 1), b = row >> 11;
    size_t base = (size_t)row * Dc + tid * 8;
    const float* xp = t ? x + base - Dc : shift_in + (size_t)b * Dc + tid * 8;
    vushort8 o;
#pragma unroll
    for (int j = 0; j < 8; j++) {
        float xv = x[base + j], pv = xp[j];
        o[j] = f2bf(xv + (pv - xv) * tmx[tid * 8 + j]);
    }
    *(vushort8*)(xxx + base) = o;
}

__global__ __launch_bounds__(256) void shift_copy(const float* __restrict__ x, float* __restrict__ out)
{
    int i = blockIdx.x * 256 + threadIdx.x;   // B*D = 8192
    int b = i >> 11, d = i & (Dc - 1);
    out[i] = x[((size_t)b * Tc + (Tc - 1)) * Dc + d];
}

// ---------------- transpose + cast f32 -> bf16 : out[C][R] = in[R][C] ----------------
__global__ __launch_bounds__(256) void transpose_cast(
    const float* __restrict__ in, unsigned short* __restrict__ out, int R, int C)
{
    __shared__ float tile[32][33];
    int ct = blockIdx.x, rt = blockIdx.y;
    int lx = threadIdx.x & 31, ly = threadIdx.x >> 5;
#pragma unroll
    for (int i = 0; i < 4; i++)
        tile[ly + i * 8][lx] = in[(size_t)(rt * 32 + ly + i * 8) * C + ct * 32 + lx];
    __syncthreads();
#pragma unroll
    for (int i = 0; i < 4; i++)
        out[(size_t)(ct * 32 + ly + i * 8) * R + rt * 32 + lx] = f2bf(tile[lx][ly + i * 8]);
}

// ---------------- WKV chunked scan (chunk=64, exact linear decomposition) ----------------
// KA: per (b,h,chunk): run recurrence from S=0 -> P[k][v], aL[k]=prod(dec)
__global__ __launch_bounds__(64) void wkv_summary(
    const unsigned short* __restrict__ kd, const unsigned short* __restrict__ vv,
    const float* __restrict__ dec, float* __restrict__ P, float* __restrict__ aL)
{
    __shared__ float pk[64 * 64 * 2];          // [t][k][{dec,kd}] 32KB
    __shared__ unsigned short vbuf[64 * 64];   // 8KB
    int blk = blockIdx.x;
    int c = blk & 31, bh = blk >> 5;
    int b = bh >> 5, h = bh & 31;
    int lane = threadIdx.x;
    size_t rowbase = ((size_t)(b * Tc + c * 64)) * Dc + h * 64;
    for (int t = 0; t < 64; t++) {
        size_t g = rowbase + (size_t)t * Dc + lane;
        pk[(t * 64 + lane) * 2 + 0] = dec[g];
        pk[(t * 64 + lane) * 2 + 1] = bf2f(kd[g]);
        vbuf[t * 64 + lane] = vv[g];
    }
    __syncthreads();
    float S[64];
#pragma unroll
    for (int k = 0; k < 64; k++) S[k] = 0.f;
    float alp = 1.f;
    for (int t = 0; t < 64; t++) {
        float myv = bf2f(vbuf[t * 64 + lane]);
        alp *= pk[(t * 64 + lane) * 2];
#pragma unroll
        for (int k = 0; k < 64; k++) {
            vfloat2 dk = *(const vfloat2*)&pk[(t * 64 + k) * 2];
            S[k] = S[k] * dk.x + dk.y * myv;
        }
    }
    size_t pb = (size_t)blk * 4096;
#pragma unroll
    for (int k = 0; k < 64; k++) P[pb + k * 64 + lane] = S[k];
    aL[(size_t)blk * 64 + lane] = alp;
}

// KB: boundary states. thread = (bh,k,v). Sb[c] = state entering chunk c. In-place over P.
__global__ __launch_bounds__(256) void wkv_states(
    const float* __restrict__ wkv_in, float* __restrict__ P /* -> Sb */,
    const float* __restrict__ aL, float* __restrict__ wkv_out)
{
    int idx = blockIdx.x * 256 + threadIdx.x;   // 524288
    int bh = idx >> 12, kv = idx & 4095, k = kv >> 6;
    float S = wkv_in[idx];
    for (int c = 0; c < 32; c++) {
        size_t off = (size_t)bh * 32 + c;
        float p = P[off * 4096 + kv];
        float a = aL[off * 64 + k];
        P[off * 4096 + kv] = S;   // Sb[c]
        S = S * a + p;
    }
    wkv_out[idx] = S;
}

// KC: replay chunk from boundary state, emit y (bf16)
__global__ __launch_bounds__(64) void wkv_y(
    const unsigned short* __restrict__ rr, const unsigned short* __restrict__ kd,
    const unsigned short* __restrict__ vv, const float* __restrict__ dec,
    const float* __restrict__ Sb, unsigned short* __restrict__ ya)
{
    __shared__ float pk[64 * 64 * 2];          // 32KB {dec,kd}
    __shared__ float rbuf[64 * 64];            // 16KB
    __shared__ unsigned short vbuf[64 * 64];   // 8KB
    int blk = blockIdx.x;
    int c = blk & 31, bh = blk >> 5;
    int b = bh >> 5, h = bh & 31;
    int lane = threadIdx.x;
    size_t rowbase = ((size_t)(b * Tc + c * 64)) * Dc + h * 64;
    for (int t = 0; t < 64; t++) {
        size_t g = rowbase + (size_t)t * Dc + lane;
        pk[(t * 64 + lane) * 2 + 0] = dec[g];
        pk[(t * 64 + lane) * 2 + 1] = bf2f(kd[g]);
        rbuf[t * 64 + lane] = bf2f(rr[g]);
        vbuf[t * 64 + lane] = vv[g];
    }
    __syncthreads();
    float S[64];
    size_t sb = (size_t)blk * 4096;
#pragma unroll
    for (int k = 0; k < 64; k++) S[k] = Sb[sb + k * 64 + lane];
    for (int t = 0; t < 64; t++) {
        float myv = bf2f(vbuf[t * 64 + lane]);
        float y[4] = {0.f, 0.f, 0.f, 0.f};
#pragma unroll
        for (int k = 0; k < 64; k++) {
            vfloat2 dk = *(const vfloat2*)&pk[(t * 64 + k) * 2];
            float rk = rbuf[t * 64 + k];
            float sk = S[k];
            y[k & 3] += rk * sk;                  // y BEFORE update
            S[k] = sk * dk.x + dk.y * myv;
        }
        ya[rowbase + (size_t)t * Dc + lane] = f2bf((y[0] + y[1]) + (y[2] + y[3]));
    }
}

// ---------------- LayerNorm(ya + v2) -> bf16 ----------------
__global__ __launch_bounds__(256) void ln_fuse(
    const unsigned short* __restrict__ ya, const unsigned short* __restrict__ v2,
    const float* __restrict__ lnw, const float* __restrict__ lnb,
    unsigned short* __restrict__ out)
{
    int row = blockIdx.x, tid = threadIdx.x;
    size_t base = (size_t)row * Dc + tid * 8;
    vushort8 a = *(const vushort8*)(ya + base);
    vushort8 b = *(const vushort8*)(v2 + base);
    float v[8]; float s = 0.f, s2 = 0.f;
#pragma unroll
    for (int j = 0; j < 8; j++) { float t = bf2f(a[j]) + bf2f(b[j]); v[j] = t; s += t; s2 += t * t; }
#pragma unroll
    for (int o = 32; o; o >>= 1) { s += __shfl_xor(s, o); s2 += __shfl_xor(s2, o); }
    __shared__ float rs[8];
    int w = tid >> 6;
    if ((tid & 63) == 0) { rs[w] = s; rs[w + 4] = s2; }
    __syncthreads();
    s  = rs[0] + rs[1] + rs[2] + rs[3];
    s2 = rs[4] + rs[5] + rs[6] + rs[7];
    float mu = s * (1.f / Dc);
    float var = s2 * (1.f / Dc) - mu * mu;
    float inv = rsqrtf(var + 1e-5f);
#pragma unroll
    for (int j = 0; j < 8; j++) {
        int d = tid * 8 + j;
        out[base + j] = f2bf((v[j] - mu) * inv * lnw[d] + lnb[d]);
    }
}

// ---------------- host ----------------
static inline void launch_gemm(int epi, const unsigned short* A, int lda,
                               const unsigned short* BT, int ldbt,
                               int M, int N, int K, EpiP ep, hipStream_t s)
{
    dim3 g((N + 127) / 128, M / 128), b(256);
    switch (epi) {
        case 0: gemm_bt<0><<<g, b, 0, s>>>(A, lda, BT, ldbt, M, N, K, ep); break;
        case 1: gemm_bt<1><<<g, b, 0, s>>>(A, lda, BT, ldbt, M, N, K, ep); break;
        case 2: gemm_bt<2><<<g, b, 0, s>>>(A, lda, BT, ldbt, M, N, K, ep); break;
        case 3: gemm_bt<3><<<g, b, 0, s>>>(A, lda, BT, ldbt, M, N, K, ep); break;
        case 4: gemm_bt<4><<<g, b, 0, s>>>(A, lda, BT, ldbt, M, N, K, ep); break;
        case 5: gemm_bt<5><<<g, b, 0, s>>>(A, lda, BT, ldbt, M, N, K, ep); break;
        case 6: gemm_bt<6><<<g, b, 0, s>>>(A, lda, BT, ldbt, M, N, K, ep); break;
    }
}

extern "C" void kernel_launch(void* const* d_in, const int* in_sizes, int n_in,
                              void* d_out, int out_size, void* d_ws, size_t ws_size,
                              hipStream_t stream)
{
    (void)in_sizes; (void)n_in; (void)out_size; (void)ws_size;
    const float* x      = (const float*)d_in[0];
    const float* shift  = (const float*)d_in[1];
    const float* wkv_in = (const float*)d_in[2];
    const float* tmx    = (const float*)d_in[3];
    const float* tmr    = (const float*)d_in[4];
    const float* tmk    = (const float*)d_in[5];
    const float* tmv    = (const float*)d_in[6];
    const float* tmw    = (const float*)d_in[7];
    const float* tmv2   = (const float*)d_in[8];
    const float* w1     = (const float*)d_in[9];
    const float* w2     = (const float*)d_in[10];
    const float* tdecay = (const float*)d_in[11];
    const float* tdw1   = (const float*)d_in[12];
    const float* tdw2   = (const float*)d_in[13];
    const float* tv2w1  = (const float*)d_in[14];
    const float* tv2w2  = (const float*)d_in[15];
    const float* Wr     = (const float*)d_in[16];
    const float* Wk     = (const float*)d_in[17];
    const float* Wv     = (const float*)d_in[18];
    const float* Wo     = (const float*)d_in[19];
    const float* lnw    = (const float*)d_in[20];
    const float* lnb    = (const float*)d_in[21];

    // ---- workspace layout (static total ~232 MB; lifetimes aliased) ----
    char* ws = (char*)d_ws;
    const size_t BF = 2 * BTDc;   // one bf16 [BT][D] tensor = 33,554,432 B
    size_t o = 0;
    auto take = [&](size_t bytes) { size_t r = o; o += (bytes + 255) & ~(size_t)255; return r; };
    unsigned short* WrT    = (unsigned short*)(ws + take((size_t)Dc * Dc * 2));
    unsigned short* WkT    = (unsigned short*)(ws + take((size_t)Dc * Dc * 2));
    unsigned short* WvT    = (unsigned short*)(ws + take((size_t)Dc * Dc * 2));
    unsigned short* WoT    = (unsigned short*)(ws + take((size_t)Dc * Dc * 2));
    unsigned short* w1T    = (unsigned short*)(ws + take((size_t)160 * Dc * 2));
    unsigned short* w2T    = (unsigned short*)(ws + take((size_t)Dc * 160 * 2));
    unsigned short* tdw1T  = (unsigned short*)(ws + take((size_t)64 * Dc * 2));
    unsigned short* tdw2T  = (unsigned short*)(ws + take((size_t)Dc * 64 * 2));
    unsigned short* tv2w1T = (unsigned short*)(ws + take((size_t)64 * Dc * 2));
    unsigned short* tv2w2T = (unsigned short*)(ws + take((size_t)Dc * 64 * 2));
    take(1 << 18);  // safety slack
    unsigned short* BUF0   = (unsigned short*)(ws + take(BF));                  // XXX -> Rb/XV2 -> (dead)
    unsigned short* MIXPRE = (unsigned short*)(ws + take((size_t)BTc * 160 * 2));
    unsigned short* BUF1   = (unsigned short*)(ws + take(BF));                  // XMbuf -> YA
    unsigned short* WT     = (unsigned short*)(ws + take((size_t)BTc * 64 * 2));
    unsigned short* T1     = (unsigned short*)(ws + take((size_t)BTc * 64 * 2));
    unsigned short* BUF2   = (unsigned short*)(ws + take(BF));                  // KDb -> V2
    unsigned short* BUF3   = (unsigned short*)(ws + take(BF));                  // Vb -> YLN
    float*          Pb     = (float*)(ws + take((size_t)128 * 32 * 4096 * 4));  // P == Sb (in-place)
    float*          ALb    = (float*)(ws + take((size_t)128 * 32 * 64 * 4));

    float* out_f     = (float*)d_out;
    float* shift_out = out_f + BTDc;
    float* wkv_out   = shift_out + (size_t)Bc * Dc;
    float* DEC       = out_f;      // f32 decay lives in the main-output region (dead before final GEMM)

    unsigned short* XXX = BUF0;
    unsigned short* Rb  = BUF0;    // after mixpre GEMM, XXX is dead
    unsigned short* XV2 = BUF0;    // after wkv_y, Rb is dead
    unsigned short* XM  = BUF1;
    unsigned short* YA  = BUF1;    // after last XM consumer
    unsigned short* KDb = BUF2;
    unsigned short* V2  = BUF2;    // after wkv_y, KDb is dead
    unsigned short* Vb  = BUF3;
    unsigned short* YLN = BUF3;    // after wkv_y, Vb is dead

    dim3 tb(256);
    // weight transposes (f32 -> bf16, N-major)
    transpose_cast<<<dim3(64, 64), tb, 0, stream>>>(Wr, WrT, Dc, Dc);
    transpose_cast<<<dim3(64, 64), tb, 0, stream>>>(Wk, WkT, Dc, Dc);
    transpose_cast<<<dim3(64, 64), tb, 0, stream>>>(Wv, WvT, Dc, Dc);
    transpose_cast<<<dim3(64, 64), tb, 0, stream>>>(Wo, WoT, Dc, Dc);
    transpose_cast<<<dim3(5, 64),  tb, 0, stream>>>(w1, w1T, Dc, 160);
    transpose_cast<<<dim3(64, 5),  tb, 0, stream>>>(w2, w2T, 160, Dc);
    transpose_cast<<<dim3(2, 64),  tb, 0, stream>>>(tdw1, tdw1T, Dc, 64);
    transpose_cast<<<dim3(64, 2),  tb, 0, stream>>>(tdw2, tdw2T, 64, Dc);
    transpose_cast<<<dim3(2, 64),  tb, 0, stream>>>(tv2w1, tv2w1T, Dc, 64);
    transpose_cast<<<dim3(64, 2),  tb, 0, stream>>>(tv2w2, tv2w2T, 64, Dc);

    prep_xxx<<<BTc, tb, 0, stream>>>(x, shift, tmx, XXX);
    shift_copy<<<32, tb, 0, stream>>>(x, shift_out);

    EpiP ep{};
    // mixpre = tanh(xxx @ w1)  (8192 x 160); XXX dead afterwards
    ep = EpiP{}; ep.ob = MIXPRE;
    launch_gemm(2, XXX, Dc, w1T, Dc, BTc, 160, Dc, ep, stream);

    const float* tmaa[5] = {tmr, tmk, tmv, tmw, tmv2};
    auto mix_into = [&](int f, unsigned short* dst) {
        EpiP e{}; e.ob = dst; e.a0 = x; e.a1 = shift; e.vec = tmaa[f];
        launch_gemm(3, MIXPRE + f * 32, 160, w2T + f * 32, 160, BTc, Dc, 32, e, stream);
    };

    // decay path: xw -> WT -> DEC (f32, in d_out region)
    mix_into(3, XM);
    ep = EpiP{}; ep.ob = WT;
    launch_gemm(2, XM, Dc, tdw1T, Dc, BTc, 64, Dc, ep, stream);
    ep = EpiP{}; ep.of = DEC; ep.vec = tdecay;
    launch_gemm(5, WT, 64, tdw2T, 64, BTc, Dc, 64, ep, stream);
    // k*(1-decay)
    mix_into(1, XM);
    ep = EpiP{}; ep.ob = KDb; ep.a0 = DEC;
    launch_gemm(4, XM, Dc, WkT, Dc, BTc, Dc, Dc, ep, stream);
    // v
    mix_into(2, XM);
    ep = EpiP{}; ep.ob = Vb;
    launch_gemm(1, XM, Dc, WvT, Dc, BTc, Dc, Dc, ep, stream);
    // r
    mix_into(0, XM);
    ep = EpiP{}; ep.ob = Rb;
    launch_gemm(1, XM, Dc, WrT, Dc, BTc, Dc, Dc, ep, stream);

    // chunked WKV scan
    wkv_summary<<<4096, dim3(64), 0, stream>>>(KDb, Vb, DEC, Pb, ALb);
    wkv_states<<<2048, tb, 0, stream>>>(wkv_in, Pb, ALb, wkv_out);
    wkv_y<<<4096, dim3(64), 0, stream>>>(Rb, KDb, Vb, DEC, Pb, YA);   // YA = BUF1 (XM dead)

    // v2 path (after scan, into dead buffers): xv2 -> BUF0, v2 -> BUF2
    mix_into(4, XV2);
    ep = EpiP{}; ep.ob = V2;
    launch_gemm(1, XV2, Dc, WvT, Dc, BTc, Dc, Dc, ep, stream);
    ep = EpiP{}; ep.ob = T1;
    launch_gemm(2, XV2, Dc, tv2w1T, Dc, BTc, 64, Dc, ep, stream);
    ep = EpiP{}; ep.ob = V2; ep.ab = V2;   // in-place add: V2 += T1 @ tv2w2
    launch_gemm(6, T1, 64, tv2w2T, 64, BTc, Dc, 64, ep, stream);

    // layernorm + output projection
    ln_fuse<<<BTc, tb, 0, stream>>>(YA, V2, lnw, lnb, YLN);           // YLN = BUF3 (Vb dead)
    ep = EpiP{}; ep.of = out_f;
    launch_gemm(0, YLN, Dc, WoT, Dc, BTc, Dc, Dc, ep, stream);        // overwrites DEC region
}

// Round 3
// 1105.373 us; speedup vs baseline: 1.5731x; 1.5731x over previous
//
#include <hip/hip_runtime.h>
#include <hip/hip_bf16.h>

// ---------------- types / helpers ----------------
typedef __attribute__((ext_vector_type(8))) short   vshort8;   // 8 x bf16 bits (4 VGPRs)
typedef __attribute__((ext_vector_type(8))) unsigned short vushort8;
typedef __attribute__((ext_vector_type(4))) float   vfloat4;
typedef __attribute__((ext_vector_type(2))) float   vfloat2;

__device__ __forceinline__ float bf2f(unsigned short h) {
    union { unsigned u; float f; } x; x.u = ((unsigned)h) << 16; return x.f;
}
__device__ __forceinline__ unsigned short f2bf(float f) {
    union { float f; unsigned u; } x; x.f = f;
    unsigned r = x.u + 0x7fffu + ((x.u >> 16) & 1u);
    return (unsigned short)(r >> 16);
}
__device__ __forceinline__ void cp16_async(const void* g, void* l) {
    __builtin_amdgcn_global_load_lds(
        (const __attribute__((address_space(1))) unsigned int*)g,
        (__attribute__((address_space(3))) unsigned int*)l, 16, 0, 0);
}

// ---------------- constants ----------------
#define Bc 4
#define Tc 2048
#define Dc 2048
#define Hc 32
#define KHc 64
#define BTc (Bc*Tc)              // 8192
#define BTDc ((size_t)BTc*Dc)    // 16,777,216
#define LP 72                    // LDS row stride (shorts): 144B = 9x16B aligned

// ---------------- GEMM: C[M,N] = A[M,K] @ BT[N,K]^T  (bf16 in, f32 acc) ----------------
struct EpiP {
    float* of;                 // f32 out
    unsigned short* ob;        // bf16 out
    const float* a0;           // aux f32 (x / decay)
    const float* a1;           // aux f32 (shift_state_in)
    const unsigned short* ab;  // aux bf16 (v2 partial)
    const float* vec;          // per-col vector (time_maa_*, time_decay)
};

template<int EPI>
__global__ __launch_bounds__(256) void gemm_bt(
    const unsigned short* __restrict__ A, int lda,
    const unsigned short* __restrict__ BT, int ldbt,
    int M, int N, int K, EpiP ep)
{
    __shared__ unsigned short lA[128 * 32];
    __shared__ unsigned short lB[128 * 32];
    const int tid  = threadIdx.x;
    const int lane = tid & 63;
    const int w    = tid >> 6;
    const int mt   = blockIdx.y, nt = blockIdx.x;
    const int wm = (w >> 1) * 64, wn = (w & 1) * 64;
    const int frow = lane & 15, fk = (lane >> 4) * 8;

    vfloat4 acc[4][4];
#pragma unroll
    for (int i = 0; i < 4; i++)
#pragma unroll
        for (int j = 0; j < 4; j++) acc[i][j] = vfloat4{0.f, 0.f, 0.f, 0.f};

    for (int k0 = 0; k0 < K; k0 += 32) {
        __syncthreads();
#pragma unroll
        for (int p = 0; p < 2; p++) {
            int idx = p * 256 + tid;
            int row = idx >> 2, colh = (idx & 3) * 8;
            cp16_async(A + (size_t)(mt * 128 + row) * lda + k0 + colh, &lA[idx * 8]);
        }
#pragma unroll
        for (int p = 0; p < 2; p++) {
            int idx = p * 256 + tid;
            int row = idx >> 2, colh = (idx & 3) * 8;
            cp16_async(BT + (size_t)(nt * 128 + row) * ldbt + k0 + colh, &lB[idx * 8]);
        }
        __syncthreads();

        vshort8 af[4], bfr[4];
#pragma unroll
        for (int m = 0; m < 4; m++) af[m]  = *(const vshort8*)&lA[(wm + m * 16 + frow) * 32 + fk];
#pragma unroll
        for (int n = 0; n < 4; n++) bfr[n] = *(const vshort8*)&lB[(wn + n * 16 + frow) * 32 + fk];
#pragma unroll
        for (int m = 0; m < 4; m++)
#pragma unroll
            for (int n = 0; n < 4; n++)
                acc[m][n] = __builtin_amdgcn_mfma_f32_16x16x32_bf16(af[m], bfr[n], acc[m][n], 0, 0, 0);
    }

    const int crow0 = mt * 128 + wm, ccol0 = nt * 128 + wn;
#pragma unroll
    for (int m = 0; m < 4; m++) {
#pragma unroll
        for (int n = 0; n < 4; n++) {
            int col = ccol0 + n * 16 + (lane & 15);
            if (col >= N) continue;
#pragma unroll
            for (int q = 0; q < 4; q++) {
                int row = crow0 + m * 16 + (lane >> 4) * 4 + q;
                float a = acc[m][n][q];
                size_t o = (size_t)row * N + col;
                if (EPI == 0) {
                    ep.of[o] = a;
                } else if (EPI == 1) {
                    ep.ob[o] = f2bf(a);
                } else if (EPI == 2) {
                    ep.ob[o] = f2bf(tanhf(a));
                } else if (EPI == 3) {                // MIX: x + (xprev-x)*(vec[col]+acc)
                    float xv = ep.a0[o];
                    int t = row & (Tc - 1);
                    float xp = t ? ep.a0[o - Dc] : ep.a1[(size_t)(row >> 11) * Dc + col];
                    ep.ob[o] = f2bf(xv + (xp - xv) * (ep.vec[col] + a));
                } else if (EPI == 4) {                // KD: acc * (1 - decay)
                    ep.ob[o] = f2bf(a * (1.f - ep.a0[o]));
                } else if (EPI == 5) {                // DECAY: exp(-exp(vec[col]+acc)) f32
                    ep.of[o] = expf(-expf(ep.vec[col] + a));
                } else if (EPI == 6) {                // ADDB: acc + bf16 aux -> bf16
                    ep.ob[o] = f2bf(a + bf2f(ep.ab[o]));
                }
            }
        }
    }
}

// ---------------- prep: xxx = x + (xprev-x)*time_maa_x  -> bf16 ----------------
__global__ __launch_bounds__(256) void prep_xxx(
    const float* __restrict__ x, const float* __restrict__ shift_in,
    const float* __restrict__ tmx, unsigned short* __restrict__ xxx)
{
    int row = blockIdx.x, tid = threadIdx.x;
    int t = row & (Tc - 1), b = row >> 11;
    size_t base = (size_t)row * Dc + tid * 8;
    const float* xp = t ? x + base - Dc : shift_in + (size_t)b * Dc + tid * 8;
    vushort8 o;
#pragma unroll
    for (int j = 0; j < 8; j++) {
        float xv = x[base + j], pv = xp[j];
        o[j] = f2bf(xv + (pv - xv) * tmx[tid * 8 + j]);
    }
    *(vushort8*)(xxx + base) = o;
}

__global__ __launch_bounds__(256) void shift_copy(const float* __restrict__ x, float* __restrict__ out)
{
    int i = blockIdx.x * 256 + threadIdx.x;   // B*D = 8192
    int b = i >> 11, d = i & (Dc - 1);
    out[i] = x[((size_t)b * Tc + (Tc - 1)) * Dc + d];
}

// ---------------- transpose + cast f32 -> bf16 : out[C][R] = in[R][C] ----------------
__global__ __launch_bounds__(256) void transpose_cast(
    const float* __restrict__ in, unsigned short* __restrict__ out, int R, int C)
{
    __shared__ float tile[32][33];
    int ct = blockIdx.x, rt = blockIdx.y;
    int lx = threadIdx.x & 31, ly = threadIdx.x >> 5;
#pragma unroll
    for (int i = 0; i < 4; i++)
        tile[ly + i * 8][lx] = in[(size_t)(rt * 32 + ly + i * 8) * C + ct * 32 + lx];
    __syncthreads();
#pragma unroll
    for (int i = 0; i < 4; i++)
        out[(size_t)(ct * 32 + ly + i * 8) * R + rt * 32 + lx] = f2bf(tile[lx][ly + i * 8]);
}

// =========== WKV chunked scan as chunked linear attention (MFMA) ===========
// chunk L=64. Aex[t,k]=prod_{u<t}dec[u,k]; G[s,k]=prod_{u>s}dec[u,k]; AL=prod_all.
// KA:  P = (G.*kd)^T @ v ; aL = AL.
// KB:  boundary states (elementwise, unchanged).
// KC:  y = rA @ Sb + ((rA @ kb^T) .* strictmask) @ v,
//      rA = r.*Aex,  kb = kd ./ (Aex.*dec).

// KA: per (b,h,chunk): 256 threads, 4 waves.
__global__ __launch_bounds__(256) void wkv_summary(
    const unsigned short* __restrict__ kd, const unsigned short* __restrict__ vv,
    const float* __restrict__ dec, float* __restrict__ P, float* __restrict__ aL)
{
    __shared__ unsigned short kb2T[64][LP];  // (G.*kd)^T  [k][s]
    __shared__ unsigned short vT[64][LP];    // v^T [vcol][s]
    __shared__ float gp[4][64];
    const int blk = blockIdx.x;
    const int c = blk & 31, bh = blk >> 5, b = bh >> 5, h = bh & 31;
    const int tid = threadIdx.x;
    const size_t rowbase = ((size_t)(b * Tc + c * 64)) * Dc + h * 64;

    // stage v transposed
    {
        int t = tid >> 2, q = tid & 3;
        const unsigned short* src = vv + rowbase + (size_t)t * Dc + q * 16;
        vushort8 a = *(const vushort8*)src;
        vushort8 b2 = *(const vushort8*)(src + 8);
#pragma unroll
        for (int j = 0; j < 8; j++) vT[q * 16 + j][t] = a[j];
#pragma unroll
        for (int j = 0; j < 8; j++) vT[q * 16 + 8 + j][t] = b2[j];
    }

    // suffix-product scan: thread k = tid&63 handles group grp = tid>>6 (16 t's)
    const int k = tid & 63, grp = tid >> 6;
    const float* decp = dec + rowbase + k;
    const unsigned short* kp = kd + rowbase + k;
    float suf_local[16];
    float pgrp = 1.f;
#pragma unroll
    for (int i = 15; i >= 0; i--) {
        int t = grp * 16 + i;
        float d = decp[(size_t)t * Dc];
        suf_local[i] = pgrp;          // prod of dec for u in (t, group_end)
        pgrp *= d;
    }
    gp[grp][k] = pgrp;
    __syncthreads();
    float suff = 1.f;
#pragma unroll
    for (int g2 = 0; g2 < 4; g2++) if (g2 > grp) suff *= gp[g2][k];
    if (grp == 0) aL[(size_t)blk * 64 + k] = pgrp * suff;   // total product
    {
        vushort8 p0, p1;
#pragma unroll
        for (int i = 0; i < 8; i++) {
            int t = grp * 16 + i;
            p0[i] = f2bf(bf2f(kp[(size_t)t * Dc]) * (suf_local[i] * suff));
        }
#pragma unroll
        for (int i = 0; i < 8; i++) {
            int t = grp * 16 + 8 + i;
            p1[i] = f2bf(bf2f(kp[(size_t)t * Dc]) * (suf_local[8 + i] * suff));
        }
        *(vushort8*)&kb2T[k][grp * 16] = p0;
        *(vushort8*)&kb2T[k][grp * 16 + 8] = p1;
    }
    __syncthreads();

    // P[k][v] = kb2T[k][s] contract vT[v][s]
    const int lane = tid & 63, w = tid >> 6;
    const int wm = (w >> 1) * 32, wn = (w & 1) * 32;
    const int frow = lane & 15, fk = (lane >> 4) * 8;
    vfloat4 acc[2][2];
#pragma unroll
    for (int m = 0; m < 2; m++)
#pragma unroll
        for (int n = 0; n < 2; n++) acc[m][n] = vfloat4{0.f, 0.f, 0.f, 0.f};
#pragma unroll
    for (int kk = 0; kk < 2; kk++) {
        vshort8 af[2], bfr[2];
#pragma unroll
        for (int m = 0; m < 2; m++) af[m]  = *(const vshort8*)&kb2T[wm + m * 16 + frow][kk * 32 + fk];
#pragma unroll
        for (int n = 0; n < 2; n++) bfr[n] = *(const vshort8*)&vT[wn + n * 16 + frow][kk * 32 + fk];
#pragma unroll
        for (int m = 0; m < 2; m++)
#pragma unroll
            for (int n = 0; n < 2; n++)
                acc[m][n] = __builtin_amdgcn_mfma_f32_16x16x32_bf16(af[m], bfr[n], acc[m][n], 0, 0, 0);
    }
    float* Pp = P + (size_t)blk * 4096;
#pragma unroll
    for (int m = 0; m < 2; m++)
#pragma unroll
        for (int n = 0; n < 2; n++) {
            int col = wn + n * 16 + (lane & 15);
#pragma unroll
            for (int q = 0; q < 4; q++) {
                int row = wm + m * 16 + (lane >> 4) * 4 + q;
                Pp[row * 64 + col] = acc[m][n][q];
            }
        }
}

// KB: boundary states. thread = (bh,k,v). In-place over P.
__global__ __launch_bounds__(256) void wkv_states(
    const float* __restrict__ wkv_in, float* __restrict__ P /* -> Sb */,
    const float* __restrict__ aL, float* __restrict__ wkv_out)
{
    int idx = blockIdx.x * 256 + threadIdx.x;   // 524288
    int bh = idx >> 12, kv = idx & 4095, k = kv >> 6;
    float S = wkv_in[idx];
    for (int c = 0; c < 32; c++) {
        size_t off = (size_t)bh * 32 + c;
        float p = P[off * 4096 + kv];
        float a = aL[off * 64 + k];
        P[off * 4096 + kv] = S;   // Sb[c]
        S = S * a + p;
    }
    wkv_out[idx] = S;
}

// KC: per (b,h,chunk): y = rA @ Sb + ((rA @ kb^T) .* strict) @ v
__global__ __launch_bounds__(256) void wkv_y(
    const unsigned short* __restrict__ rr, const unsigned short* __restrict__ kd,
    const unsigned short* __restrict__ vv, const float* __restrict__ dec,
    const float* __restrict__ Sb, unsigned short* __restrict__ ya)
{
    __shared__ unsigned short rA[64][LP];    // r .* Aex   [t][k]
    __shared__ unsigned short kbL[64][LP];   // kd ./ Aincl [s][k]
    __shared__ unsigned short vT[64][LP];    // v^T [vcol][s]
    __shared__ unsigned short SbT[64][LP];   // Sb^T [vcol][k]
    __shared__ unsigned short QiM[64][LP];   // masked Qi [t][s]
    __shared__ float gp[4][64];
    const int blk = blockIdx.x;
    const int c = blk & 31, bh = blk >> 5, b = bh >> 5, h = bh & 31;
    const int tid = threadIdx.x;
    const size_t rowbase = ((size_t)(b * Tc + c * 64)) * Dc + h * 64;

    // stage v^T and Sb^T
    {
        int t = tid >> 2, q = tid & 3;
        const unsigned short* src = vv + rowbase + (size_t)t * Dc + q * 16;
        vushort8 a = *(const vushort8*)src;
        vushort8 b2 = *(const vushort8*)(src + 8);
#pragma unroll
        for (int j = 0; j < 8; j++) vT[q * 16 + j][t] = a[j];
#pragma unroll
        for (int j = 0; j < 8; j++) vT[q * 16 + 8 + j][t] = b2[j];
        const float* sp = Sb + (size_t)blk * 4096 + t * 64 + q * 16;
#pragma unroll
        for (int j = 0; j < 16; j++) SbT[q * 16 + j][t] = f2bf(sp[j]);
    }

    // prefix-product scan: thread k = tid&63, group grp = tid>>6
    const int k = tid & 63, grp = tid >> 6;
    const float* decp = dec + rowbase + k;
    const unsigned short* rp = rr + rowbase + k;
    const unsigned short* kp = kd + rowbase + k;
    float pref_local[16];
    float pgrp = 1.f;
#pragma unroll
    for (int i = 0; i < 16; i++) {
        int t = grp * 16 + i;
        float d = decp[(size_t)t * Dc];
        pref_local[i] = pgrp;         // exclusive prefix within group
        pgrp *= d;
    }
    gp[grp][k] = pgrp;
    __syncthreads();
    float pref = 1.f;
#pragma unroll
    for (int g2 = 0; g2 < 4; g2++) if (g2 < grp) pref *= gp[g2][k];
#pragma unroll
    for (int i = 0; i < 16; i++) {
        int t = grp * 16 + i;
        float Aex  = pref * pref_local[i];
        float Ainc = pref * (i < 15 ? pref_local[i + 1] : pgrp);
        rA[t][k]  = f2bf(bf2f(rp[(size_t)t * Dc]) * Aex);
        kbL[t][k] = f2bf(bf2f(kp[(size_t)t * Dc]) / Ainc);
    }
    __syncthreads();

    const int lane = tid & 63, w = tid >> 6;
    const int wm = (w >> 1) * 32, wn = (w & 1) * 32;
    const int frow = lane & 15, fk = (lane >> 4) * 8;

    // GEMM1: Qi[t][s] = rA[t][k] contract kbL[s][k]
    vfloat4 acc[2][2];
#pragma unroll
    for (int m = 0; m < 2; m++)
#pragma unroll
        for (int n = 0; n < 2; n++) acc[m][n] = vfloat4{0.f, 0.f, 0.f, 0.f};
#pragma unroll
    for (int kk = 0; kk < 2; kk++) {
        vshort8 af[2], bfr[2];
#pragma unroll
        for (int m = 0; m < 2; m++) af[m]  = *(const vshort8*)&rA[wm + m * 16 + frow][kk * 32 + fk];
#pragma unroll
        for (int n = 0; n < 2; n++) bfr[n] = *(const vshort8*)&kbL[wn + n * 16 + frow][kk * 32 + fk];
#pragma unroll
        for (int m = 0; m < 2; m++)
#pragma unroll
            for (int n = 0; n < 2; n++)
                acc[m][n] = __builtin_amdgcn_mfma_f32_16x16x32_bf16(af[m], bfr[n], acc[m][n], 0, 0, 0);
    }
    // strict causal mask (keep s < t), write QiM bf16
#pragma unroll
    for (int m = 0; m < 2; m++)
#pragma unroll
        for (int n = 0; n < 2; n++) {
            int s = wn + n * 16 + (lane & 15);
#pragma unroll
            for (int q = 0; q < 4; q++) {
                int t = wm + m * 16 + (lane >> 4) * 4 + q;
                QiM[t][s] = f2bf(s < t ? acc[m][n][q] : 0.f);
            }
        }
    __syncthreads();

    // GEMM2+3: y[t][v] = QiM[t][s] contract vT[v][s] + rA[t][k] contract SbT[v][k]
#pragma unroll
    for (int m = 0; m < 2; m++)
#pragma unroll
        for (int n = 0; n < 2; n++) acc[m][n] = vfloat4{0.f, 0.f, 0.f, 0.f};
#pragma unroll
    for (int kk = 0; kk < 2; kk++) {
        vshort8 af[2], bfr[2];
#pragma unroll
        for (int m = 0; m < 2; m++) af[m]  = *(const vshort8*)&QiM[wm + m * 16 + frow][kk * 32 + fk];
#pragma unroll
        for (int n = 0; n < 2; n++) bfr[n] = *(const vshort8*)&vT[wn + n * 16 + frow][kk * 32 + fk];
#pragma unroll
        for (int m = 0; m < 2; m++)
#pragma unroll
            for (int n = 0; n < 2; n++)
                acc[m][n] = __builtin_amdgcn_mfma_f32_16x16x32_bf16(af[m], bfr[n], acc[m][n], 0, 0, 0);
    }
#pragma unroll
    for (int kk = 0; kk < 2; kk++) {
        vshort8 af[2], bfr[2];
#pragma unroll
        for (int m = 0; m < 2; m++) af[m]  = *(const vshort8*)&rA[wm + m * 16 + frow][kk * 32 + fk];
#pragma unroll
        for (int n = 0; n < 2; n++) bfr[n] = *(const vshort8*)&SbT[wn + n * 16 + frow][kk * 32 + fk];
#pragma unroll
        for (int m = 0; m < 2; m++)
#pragma unroll
            for (int n = 0; n < 2; n++)
                acc[m][n] = __builtin_amdgcn_mfma_f32_16x16x32_bf16(af[m], bfr[n], acc[m][n], 0, 0, 0);
    }
    // store y
#pragma unroll
    for (int m = 0; m < 2; m++)
#pragma unroll
        for (int n = 0; n < 2; n++) {
            int col = wn + n * 16 + (lane & 15);
#pragma unroll
            for (int q = 0; q < 4; q++) {
                int t = wm + m * 16 + (lane >> 4) * 4 + q;
                ya[rowbase + (size_t)t * Dc + col] = f2bf(acc[m][n][q]);
            }
        }
}

// ---------------- LayerNorm(ya + v2) -> bf16 ----------------
__global__ __launch_bounds__(256) void ln_fuse(
    const unsigned short* __restrict__ ya, const unsigned short* __restrict__ v2,
    const float* __restrict__ lnw, const float* __restrict__ lnb,
    unsigned short* __restrict__ out)
{
    int row = blockIdx.x, tid = threadIdx.x;
    size_t base = (size_t)row * Dc + tid * 8;
    vushort8 a = *(const vushort8*)(ya + base);
    vushort8 b = *(const vushort8*)(v2 + base);
    float v[8]; float s = 0.f, s2 = 0.f;
#pragma unroll
    for (int j = 0; j < 8; j++) { float t = bf2f(a[j]) + bf2f(b[j]); v[j] = t; s += t; s2 += t * t; }
#pragma unroll
    for (int o = 32; o; o >>= 1) { s += __shfl_xor(s, o); s2 += __shfl_xor(s2, o); }
    __shared__ float rs[8];
    int w = tid >> 6;
    if ((tid & 63) == 0) { rs[w] = s; rs[w + 4] = s2; }
    __syncthreads();
    s  = rs[0] + rs[1] + rs[2] + rs[3];
    s2 = rs[4] + rs[5] + rs[6] + rs[7];
    float mu = s * (1.f / Dc);
    float var = s2 * (1.f / Dc) - mu * mu;
    float inv = rsqrtf(var + 1e-5f);
#pragma unroll
    for (int j = 0; j < 8; j++) {
        int d = tid * 8 + j;
        out[base + j] = f2bf((v[j] - mu) * inv * lnw[d] + lnb[d]);
    }
}

// ---------------- host ----------------
static inline void launch_gemm(int epi, const unsigned short* A, int lda,
                               const unsigned short* BT, int ldbt,
                               int M, int N, int K, EpiP ep, hipStream_t s)
{
    dim3 g((N + 127) / 128, M / 128), b(256);
    switch (epi) {
        case 0: gemm_bt<0><<<g, b, 0, s>>>(A, lda, BT, ldbt, M, N, K, ep); break;
        case 1: gemm_bt<1><<<g, b, 0, s>>>(A, lda, BT, ldbt, M, N, K, ep); break;
        case 2: gemm_bt<2><<<g, b, 0, s>>>(A, lda, BT, ldbt, M, N, K, ep); break;
        case 3: gemm_bt<3><<<g, b, 0, s>>>(A, lda, BT, ldbt, M, N, K, ep); break;
        case 4: gemm_bt<4><<<g, b, 0, s>>>(A, lda, BT, ldbt, M, N, K, ep); break;
        case 5: gemm_bt<5><<<g, b, 0, s>>>(A, lda, BT, ldbt, M, N, K, ep); break;
        case 6: gemm_bt<6><<<g, b, 0, s>>>(A, lda, BT, ldbt, M, N, K, ep); break;
    }
}

extern "C" void kernel_launch(void* const* d_in, const int* in_sizes, int n_in,
                              void* d_out, int out_size, void* d_ws, size_t ws_size,
                              hipStream_t stream)
{
    (void)in_sizes; (void)n_in; (void)out_size; (void)ws_size;
    const float* x      = (const float*)d_in[0];
    const float* shift  = (const float*)d_in[1];
    const float* wkv_in = (const float*)d_in[2];
    const float* tmx    = (const float*)d_in[3];
    const float* tmr    = (const float*)d_in[4];
    const float* tmk    = (const float*)d_in[5];
    const float* tmv    = (const float*)d_in[6];
    const float* tmw    = (const float*)d_in[7];
    const float* tmv2   = (const float*)d_in[8];
    const float* w1     = (const float*)d_in[9];
    const float* w2     = (const float*)d_in[10];
    const float* tdecay = (const float*)d_in[11];
    const float* tdw1   = (const float*)d_in[12];
    const float* tdw2   = (const float*)d_in[13];
    const float* tv2w1  = (const float*)d_in[14];
    const float* tv2w2  = (const float*)d_in[15];
    const float* Wr     = (const float*)d_in[16];
    const float* Wk     = (const float*)d_in[17];
    const float* Wv     = (const float*)d_in[18];
    const float* Wo     = (const float*)d_in[19];
    const float* lnw    = (const float*)d_in[20];
    const float* lnb    = (const float*)d_in[21];

    // ---- workspace layout (lifetimes aliased) ----
    char* ws = (char*)d_ws;
    const size_t BF = 2 * BTDc;   // one bf16 [BT][D] tensor = 33,554,432 B
    size_t o = 0;
    auto take = [&](size_t bytes) { size_t r = o; o += (bytes + 255) & ~(size_t)255; return r; };
    unsigned short* WrT    = (unsigned short*)(ws + take((size_t)Dc * Dc * 2));
    unsigned short* WkT    = (unsigned short*)(ws + take((size_t)Dc * Dc * 2));
    unsigned short* WvT    = (unsigned short*)(ws + take((size_t)Dc * Dc * 2));
    unsigned short* WoT    = (unsigned short*)(ws + take((size_t)Dc * Dc * 2));
    unsigned short* w1T    = (unsigned short*)(ws + take((size_t)160 * Dc * 2));
    unsigned short* w2T    = (unsigned short*)(ws + take((size_t)Dc * 160 * 2));
    unsigned short* tdw1T  = (unsigned short*)(ws + take((size_t)64 * Dc * 2));
    unsigned short* tdw2T  = (unsigned short*)(ws + take((size_t)Dc * 64 * 2));
    unsigned short* tv2w1T = (unsigned short*)(ws + take((size_t)64 * Dc * 2));
    unsigned short* tv2w2T = (unsigned short*)(ws + take((size_t)Dc * 64 * 2));
    take(1 << 18);  // safety slack
    unsigned short* BUF0   = (unsigned short*)(ws + take(BF));                  // XXX -> Rb/XV2
    unsigned short* MIXPRE = (unsigned short*)(ws + take((size_t)BTc * 160 * 2));
    unsigned short* BUF1   = (unsigned short*)(ws + take(BF));                  // XM -> YA
    unsigned short* WT     = (unsigned short*)(ws + take((size_t)BTc * 64 * 2));
    unsigned short* T1     = (unsigned short*)(ws + take((size_t)BTc * 64 * 2));
    unsigned short* BUF2   = (unsigned short*)(ws + take(BF));                  // KDb -> V2
    unsigned short* BUF3   = (unsigned short*)(ws + take(BF));                  // Vb -> YLN
    float*          Pb     = (float*)(ws + take((size_t)128 * 32 * 4096 * 4));  // P == Sb (in-place)
    float*          ALb    = (float*)(ws + take((size_t)128 * 32 * 64 * 4));

    float* out_f     = (float*)d_out;
    float* shift_out = out_f + BTDc;
    float* wkv_out   = shift_out + (size_t)Bc * Dc;
    float* DEC       = out_f;      // f32 decay lives in the main-output region (dead before final GEMM)

    unsigned short* XXX = BUF0;
    unsigned short* Rb  = BUF0;
    unsigned short* XV2 = BUF0;
    unsigned short* XM  = BUF1;
    unsigned short* YA  = BUF1;
    unsigned short* KDb = BUF2;
    unsigned short* V2  = BUF2;
    unsigned short* Vb  = BUF3;
    unsigned short* YLN = BUF3;

    dim3 tb(256);
    transpose_cast<<<dim3(64, 64), tb, 0, stream>>>(Wr, WrT, Dc, Dc);
    transpose_cast<<<dim3(64, 64), tb, 0, stream>>>(Wk, WkT, Dc, Dc);
    transpose_cast<<<dim3(64, 64), tb, 0, stream>>>(Wv, WvT, Dc, Dc);
    transpose_cast<<<dim3(64, 64), tb, 0, stream>>>(Wo, WoT, Dc, Dc);
    transpose_cast<<<dim3(5, 64),  tb, 0, stream>>>(w1, w1T, Dc, 160);
    transpose_cast<<<dim3(64, 5),  tb, 0, stream>>>(w2, w2T, 160, Dc);
    transpose_cast<<<dim3(2, 64),  tb, 0, stream>>>(tdw1, tdw1T, Dc, 64);
    transpose_cast<<<dim3(64, 2),  tb, 0, stream>>>(tdw2, tdw2T, 64, Dc);
    transpose_cast<<<dim3(2, 64),  tb, 0, stream>>>(tv2w1, tv2w1T, Dc, 64);
    transpose_cast<<<dim3(64, 2),  tb, 0, stream>>>(tv2w2, tv2w2T, 64, Dc);

    prep_xxx<<<BTc, tb, 0, stream>>>(x, shift, tmx, XXX);
    shift_copy<<<32, tb, 0, stream>>>(x, shift_out);

    EpiP ep{};
    ep = EpiP{}; ep.ob = MIXPRE;
    launch_gemm(2, XXX, Dc, w1T, Dc, BTc, 160, Dc, ep, stream);

    const float* tmaa[5] = {tmr, tmk, tmv, tmw, tmv2};
    auto mix_into = [&](int f, unsigned short* dst) {
        EpiP e{}; e.ob = dst; e.a0 = x; e.a1 = shift; e.vec = tmaa[f];
        launch_gemm(3, MIXPRE + f * 32, 160, w2T + f * 32, 160, BTc, Dc, 32, e, stream);
    };

    // decay path
    mix_into(3, XM);
    ep = EpiP{}; ep.ob = WT;
    launch_gemm(2, XM, Dc, tdw1T, Dc, BTc, 64, Dc, ep, stream);
    ep = EpiP{}; ep.of = DEC; ep.vec = tdecay;
    launch_gemm(5, WT, 64, tdw2T, 64, BTc, Dc, 64, ep, stream);
    // k*(1-decay)
    mix_into(1, XM);
    ep = EpiP{}; ep.ob = KDb; ep.a0 = DEC;
    launch_gemm(4, XM, Dc, WkT, Dc, BTc, Dc, Dc, ep, stream);
    // v
    mix_into(2, XM);
    ep = EpiP{}; ep.ob = Vb;
    launch_gemm(1, XM, Dc, WvT, Dc, BTc, Dc, Dc, ep, stream);
    // r
    mix_into(0, XM);
    ep = EpiP{}; ep.ob = Rb;
    launch_gemm(1, XM, Dc, WrT, Dc, BTc, Dc, Dc, ep, stream);

    // chunked WKV scan (MFMA)
    wkv_summary<<<4096, tb, 0, stream>>>(KDb, Vb, DEC, Pb, ALb);
    wkv_states<<<2048, tb, 0, stream>>>(wkv_in, Pb, ALb, wkv_out);
    wkv_y<<<4096, tb, 0, stream>>>(Rb, KDb, Vb, DEC, Pb, YA);

    // v2 path (into dead buffers)
    mix_into(4, XV2);
    ep = EpiP{}; ep.ob = V2;
    launch_gemm(1, XV2, Dc, WvT, Dc, BTc, Dc, Dc, ep, stream);
    ep = EpiP{}; ep.ob = T1;
    launch_gemm(2, XV2, Dc, tv2w1T, Dc, BTc, 64, Dc, ep, stream);
    ep = EpiP{}; ep.ob = V2; ep.ab = V2;   // in-place add
    launch_gemm(6, T1, 64, tv2w2T, 64, BTc, Dc, 64, ep, stream);

    // layernorm + output projection
    ln_fuse<<<BTc, tb, 0, stream>>>(YA, V2, lnw, lnb, YLN);
    ep = EpiP{}; ep.of = out_f;
    launch_gemm(0, YLN, Dc, WoT, Dc, BTc, Dc, Dc, ep, stream);
}

// Round 5
// 913.194 us; speedup vs baseline: 1.9042x; 1.2104x over previous
//
#include <hip/hip_runtime.h>
#include <hip/hip_bf16.h>

// ---------------- types / helpers ----------------
typedef __attribute__((ext_vector_type(8))) short   vshort8;   // 8 x bf16 bits (4 VGPRs)
typedef __attribute__((ext_vector_type(8))) unsigned short vushort8;
typedef __attribute__((ext_vector_type(4))) float   vfloat4;
typedef __attribute__((ext_vector_type(2))) float   vfloat2;

__device__ __forceinline__ float bf2f(unsigned short h) {
    union { unsigned u; float f; } x; x.u = ((unsigned)h) << 16; return x.f;
}
__device__ __forceinline__ unsigned short f2bf(float f) {
    union { float f; unsigned u; } x; x.f = f;
    unsigned r = x.u + 0x7fffu + ((x.u >> 16) & 1u);
    return (unsigned short)(r >> 16);
}
__device__ __forceinline__ void cp16_async(const void* g, void* l) {
    __builtin_amdgcn_global_load_lds(
        (const __attribute__((address_space(1))) unsigned int*)g,
        (__attribute__((address_space(3))) unsigned int*)l, 16, 0, 0);
}

// ---------------- constants ----------------
#define Bc 4
#define Tc 2048
#define Dc 2048
#define Hc 32
#define KHc 64
#define BTc (Bc*Tc)              // 8192
#define BTDc ((size_t)BTc*Dc)    // 16,777,216
#define LP 72                    // LDS row stride (shorts) for scan kernels

struct EpiP {
    float* of;                 // f32 out
    unsigned short* ob;        // bf16 out
    const float* a0;           // aux f32 (x / decay)
    const float* a1;           // aux f32 (shift_state_in)
    const unsigned short* ab;  // aux bf16 (v2 partial)
    const float* vec;          // per-col vector (time_maa_*, time_decay)
};

template<int EPI>
__device__ __forceinline__ void epi_store(float a, int row, int col, int N, const EpiP& ep)
{
    size_t o = (size_t)row * N + col;
    if (EPI == 0) {
        ep.of[o] = a;
    } else if (EPI == 1) {
        ep.ob[o] = f2bf(a);
    } else if (EPI == 2) {
        ep.ob[o] = f2bf(tanhf(a));
    } else if (EPI == 3) {                // MIX: x + (xprev-x)*(vec[col]+acc)
        float xv = ep.a0[o];
        int t = row & (Tc - 1);
        float xp = t ? ep.a0[o - Dc] : ep.a1[(size_t)(row >> 11) * Dc + col];
        ep.ob[o] = f2bf(xv + (xp - xv) * (ep.vec[col] + a));
    } else if (EPI == 4) {                // KD: acc * (1 - decay)
        ep.ob[o] = f2bf(a * (1.f - ep.a0[o]));
    } else if (EPI == 5) {                // DECAY: exp(-exp(vec[col]+acc)) f32
        ep.of[o] = expf(-expf(ep.vec[col] + a));
    } else if (EPI == 6) {                // ADDB: acc + bf16 aux -> bf16
        ep.ob[o] = f2bf(a + bf2f(ep.ab[o]));
    }
}

// ============ GEMM-128 (old m97-style), used for odd N (160 / 64) ============
template<int EPI>
__global__ __launch_bounds__(256) void gemm_bt(
    const unsigned short* __restrict__ A, int lda,
    const unsigned short* __restrict__ BT, int ldbt,
    int M, int N, int K, EpiP ep)
{
    __shared__ unsigned short lA[128 * 32];
    __shared__ unsigned short lB[128 * 32];
    const int tid  = threadIdx.x;
    const int lane = tid & 63;
    const int w    = tid >> 6;
    const int mt   = blockIdx.y, nt = blockIdx.x;
    const int wm = (w >> 1) * 64, wn = (w & 1) * 64;
    const int frow = lane & 15, fk = (lane >> 4) * 8;

    vfloat4 acc[4][4];
#pragma unroll
    for (int i = 0; i < 4; i++)
#pragma unroll
        for (int j = 0; j < 4; j++) acc[i][j] = vfloat4{0.f, 0.f, 0.f, 0.f};

    for (int k0 = 0; k0 < K; k0 += 32) {
        __syncthreads();
#pragma unroll
        for (int p = 0; p < 2; p++) {
            int idx = p * 256 + tid;
            int row = idx >> 2, colh = (idx & 3) * 8;
            cp16_async(A + (size_t)(mt * 128 + row) * lda + k0 + colh, &lA[idx * 8]);
        }
#pragma unroll
        for (int p = 0; p < 2; p++) {
            int idx = p * 256 + tid;
            int row = idx >> 2, colh = (idx & 3) * 8;
            cp16_async(BT + (size_t)(nt * 128 + row) * ldbt + k0 + colh, &lB[idx * 8]);
        }
        __syncthreads();

        vshort8 af[4], bfr[4];
#pragma unroll
        for (int m = 0; m < 4; m++) af[m]  = *(const vshort8*)&lA[(wm + m * 16 + frow) * 32 + fk];
#pragma unroll
        for (int n = 0; n < 4; n++) bfr[n] = *(const vshort8*)&lB[(wn + n * 16 + frow) * 32 + fk];
#pragma unroll
        for (int m = 0; m < 4; m++)
#pragma unroll
            for (int n = 0; n < 4; n++)
                acc[m][n] = __builtin_amdgcn_mfma_f32_16x16x32_bf16(af[m], bfr[n], acc[m][n], 0, 0, 0);
    }

    const int crow0 = mt * 128 + wm, ccol0 = nt * 128 + wn;
#pragma unroll
    for (int m = 0; m < 4; m++)
#pragma unroll
        for (int n = 0; n < 4; n++) {
            int col = ccol0 + n * 16 + (lane & 15);
            if (col >= N) continue;
#pragma unroll
            for (int q = 0; q < 4; q++) {
                int row = crow0 + m * 16 + (lane >> 4) * 4 + q;
                epi_store<EPI>(acc[m][n][q], row, col, N, ep);
            }
        }
}

// ============ GEMM-256: 256x256 tile, BK=32, 8 waves, triple-buffer, counted vmcnt ============
// LDS swizzle: 16B chunk index XORed with (row&3) -> conflict-free ds_read_b128.
// Write side: linear LDS dest (global_load_lds), inverse-permuted global source.
// Buffer for tile t is t % 3; `buf` tracks kt % 3, `sb` tracks (kt+2) % 3.
template<int EPI>
__global__ __launch_bounds__(512, 1) void gemm256(
    const unsigned short* __restrict__ A, int lda,
    const unsigned short* __restrict__ BT, int ldbt,
    int M, int N, int K, EpiP ep)
{
    __shared__ unsigned short sh[3 * 16384];   // 3 bufs x (A 8192 + B 8192 shorts) = 96 KB
    const int tid  = threadIdx.x;
    const int lane = tid & 63;
    const int w    = tid >> 6;
    const int mt   = blockIdx.y, nt = blockIdx.x;
    const int wm = (w >> 2) * 128, wn = (w & 3) * 64;
    const int frow = lane & 15;
    const int cswz = ((lane >> 4) ^ (frow & 3)) * 8;   // swizzled chunk offset (shorts), constant/lane
    const int arow0 = mt * 256, brow0 = nt * 256;

    vfloat4 acc[8][4];
#pragma unroll
    for (int i = 0; i < 8; i++)
#pragma unroll
        for (int j = 0; j < 4; j++) acc[i][j] = vfloat4{0.f, 0.f, 0.f, 0.f};

    const int NT = K >> 5;

    auto stage = [&](int kt, int sbuf) {
        int k0 = kt << 5;
        unsigned short* dst = &sh[sbuf * 16384];
#pragma unroll
        for (int i = 0; i < 2; i++) {
            int idx = i * 512 + tid;
            int row = idx >> 2;
            int ch  = (idx & 3) ^ (row & 3);
            cp16_async(A + (size_t)(arow0 + row) * lda + k0 + ch * 8, dst + idx * 8);
        }
#pragma unroll
        for (int i = 0; i < 2; i++) {
            int idx = i * 512 + tid;
            int row = idx >> 2;
            int ch  = (idx & 3) ^ (row & 3);
            cp16_async(BT + (size_t)(brow0 + row) * ldbt + k0 + ch * 8, dst + 8192 + idx * 8);
        }
    };

    // prologue: stage tiles 0 and 1; wait tile 0 only (tile 1 stays in flight)
    stage(0, 0);
    if (NT > 1) {
        stage(1, 1);
        asm volatile("s_waitcnt vmcnt(4)" ::: "memory");
    } else {
        asm volatile("s_waitcnt vmcnt(0)" ::: "memory");
    }
    __builtin_amdgcn_s_barrier();

    int buf = 0, sb = 2;   // buf = kt % 3; sb = (kt+2) % 3
    for (int kt = 0; kt < NT; kt++) {
        if (kt + 2 < NT) stage(kt + 2, sb);
        const unsigned short* Ab = &sh[buf * 16384];
        const unsigned short* Bb = Ab + 8192;

        vshort8 af[8], bfv[4];
#pragma unroll
        for (int m = 0; m < 8; m++)
            af[m] = *(const vshort8*)&Ab[(wm + m * 16 + frow) * 32 + cswz];
#pragma unroll
        for (int n = 0; n < 4; n++)
            bfv[n] = *(const vshort8*)&Bb[(wn + n * 16 + frow) * 32 + cswz];

        __builtin_amdgcn_s_setprio(1);
#pragma unroll
        for (int m = 0; m < 8; m++)
#pragma unroll
            for (int n = 0; n < 4; n++)
                acc[m][n] = __builtin_amdgcn_mfma_f32_16x16x32_bf16(af[m], bfv[n], acc[m][n], 0, 0, 0);
        __builtin_amdgcn_s_setprio(0);

        if (kt + 1 < NT) {
            // retire tile kt+1; keep tile kt+2 (if staged) in flight across the barrier
            if (kt + 2 < NT) asm volatile("s_waitcnt vmcnt(4)" ::: "memory");
            else             asm volatile("s_waitcnt vmcnt(0)" ::: "memory");
            asm volatile("s_waitcnt lgkmcnt(0)" ::: "memory");
            __builtin_amdgcn_s_barrier();
        }
        buf = (buf == 2) ? 0 : buf + 1;
        sb  = (sb  == 2) ? 0 : sb  + 1;
    }

    const int crow0 = arow0 + wm, ccol0 = brow0 + wn;
#pragma unroll
    for (int m = 0; m < 8; m++)
#pragma unroll
        for (int n = 0; n < 4; n++) {
            int col = ccol0 + n * 16 + (lane & 15);
#pragma unroll
            for (int q = 0; q < 4; q++) {
                int row = crow0 + m * 16 + (lane >> 4) * 4 + q;
                epi_store<EPI>(acc[m][n][q], row, col, N, ep);
            }
        }
}

// ---------------- prep: xxx = x + (xprev-x)*time_maa_x  -> bf16 ----------------
__global__ __launch_bounds__(256) void prep_xxx(
    const float* __restrict__ x, const float* __restrict__ shift_in,
    const float* __restrict__ tmx, unsigned short* __restrict__ xxx)
{
    int row = blockIdx.x, tid = threadIdx.x;
    int t = row & (Tc - 1), b = row >> 11;
    size_t base = (size_t)row * Dc + tid * 8;
    const float* xp = t ? x + base - Dc : shift_in + (size_t)b * Dc + tid * 8;
    vushort8 o;
#pragma unroll
    for (int j = 0; j < 8; j++) {
        float xv = x[base + j], pv = xp[j];
        o[j] = f2bf(xv + (pv - xv) * tmx[tid * 8 + j]);
    }
    *(vushort8*)(xxx + base) = o;
}

__global__ __launch_bounds__(256) void shift_copy(const float* __restrict__ x, float* __restrict__ out)
{
    int i = blockIdx.x * 256 + threadIdx.x;   // B*D = 8192
    int b = i >> 11, d = i & (Dc - 1);
    out[i] = x[((size_t)b * Tc + (Tc - 1)) * Dc + d];
}

// ---------------- transpose + cast f32 -> bf16 : out[C][R] = in[R][C] ----------------
__global__ __launch_bounds__(256) void transpose_cast(
    const float* __restrict__ in, unsigned short* __restrict__ out, int R, int C)
{
    __shared__ float tile[32][33];
    int ct = blockIdx.x, rt = blockIdx.y;
    int lx = threadIdx.x & 31, ly = threadIdx.x >> 5;
#pragma unroll
    for (int i = 0; i < 4; i++)
        tile[ly + i * 8][lx] = in[(size_t)(rt * 32 + ly + i * 8) * C + ct * 32 + lx];
    __syncthreads();
#pragma unroll
    for (int i = 0; i < 4; i++)
        out[(size_t)(ct * 32 + ly + i * 8) * R + rt * 32 + lx] = f2bf(tile[lx][ly + i * 8]);
}

// =========== WKV chunked scan as chunked linear attention (MFMA) ===========
__global__ __launch_bounds__(256) void wkv_summary(
    const unsigned short* __restrict__ kd, const unsigned short* __restrict__ vv,
    const float* __restrict__ dec, float* __restrict__ P, float* __restrict__ aL)
{
    __shared__ unsigned short kb2T[64][LP];
    __shared__ unsigned short vT[64][LP];
    __shared__ float gp[4][64];
    const int blk = blockIdx.x;
    const int c = blk & 31, bh = blk >> 5, b = bh >> 5, h = bh & 31;
    const int tid = threadIdx.x;
    const size_t rowbase = ((size_t)(b * Tc + c * 64)) * Dc + h * 64;

    {
        int t = tid >> 2, q = tid & 3;
        const unsigned short* src = vv + rowbase + (size_t)t * Dc + q * 16;
        vushort8 a = *(const vushort8*)src;
        vushort8 b2 = *(const vushort8*)(src + 8);
#pragma unroll
        for (int j = 0; j < 8; j++) vT[q * 16 + j][t] = a[j];
#pragma unroll
        for (int j = 0; j < 8; j++) vT[q * 16 + 8 + j][t] = b2[j];
    }

    const int k = tid & 63, grp = tid >> 6;
    const float* decp = dec + rowbase + k;
    const unsigned short* kp = kd + rowbase + k;
    float suf_local[16];
    float pgrp = 1.f;
#pragma unroll
    for (int i = 15; i >= 0; i--) {
        int t = grp * 16 + i;
        float d = decp[(size_t)t * Dc];
        suf_local[i] = pgrp;
        pgrp *= d;
    }
    gp[grp][k] = pgrp;
    __syncthreads();
    float suff = 1.f;
#pragma unroll
    for (int g2 = 0; g2 < 4; g2++) if (g2 > grp) suff *= gp[g2][k];
    if (grp == 0) aL[(size_t)blk * 64 + k] = pgrp * suff;
    {
        vushort8 p0, p1;
#pragma unroll
        for (int i = 0; i < 8; i++) {
            int t = grp * 16 + i;
            p0[i] = f2bf(bf2f(kp[(size_t)t * Dc]) * (suf_local[i] * suff));
        }
#pragma unroll
        for (int i = 0; i < 8; i++) {
            int t = grp * 16 + 8 + i;
            p1[i] = f2bf(bf2f(kp[(size_t)t * Dc]) * (suf_local[8 + i] * suff));
        }
        *(vushort8*)&kb2T[k][grp * 16] = p0;
        *(vushort8*)&kb2T[k][grp * 16 + 8] = p1;
    }
    __syncthreads();

    const int lane = tid & 63, w = tid >> 6;
    const int wm = (w >> 1) * 32, wn = (w & 1) * 32;
    const int frow = lane & 15, fk = (lane >> 4) * 8;
    vfloat4 acc[2][2];
#pragma unroll
    for (int m = 0; m < 2; m++)
#pragma unroll
        for (int n = 0; n < 2; n++) acc[m][n] = vfloat4{0.f, 0.f, 0.f, 0.f};
#pragma unroll
    for (int kk = 0; kk < 2; kk++) {
        vshort8 af[2], bfr[2];
#pragma unroll
        for (int m = 0; m < 2; m++) af[m]  = *(const vshort8*)&kb2T[wm + m * 16 + frow][kk * 32 + fk];
#pragma unroll
        for (int n = 0; n < 2; n++) bfr[n] = *(const vshort8*)&vT[wn + n * 16 + frow][kk * 32 + fk];
#pragma unroll
        for (int m = 0; m < 2; m++)
#pragma unroll
            for (int n = 0; n < 2; n++)
                acc[m][n] = __builtin_amdgcn_mfma_f32_16x16x32_bf16(af[m], bfr[n], acc[m][n], 0, 0, 0);
    }
    float* Pp = P + (size_t)blk * 4096;
#pragma unroll
    for (int m = 0; m < 2; m++)
#pragma unroll
        for (int n = 0; n < 2; n++) {
            int col = wn + n * 16 + (lane & 15);
#pragma unroll
            for (int q = 0; q < 4; q++) {
                int row = wm + m * 16 + (lane >> 4) * 4 + q;
                Pp[row * 64 + col] = acc[m][n][q];
            }
        }
}

__global__ __launch_bounds__(256) void wkv_states(
    const float* __restrict__ wkv_in, float* __restrict__ P /* -> Sb */,
    const float* __restrict__ aL, float* __restrict__ wkv_out)
{
    int idx = blockIdx.x * 256 + threadIdx.x;   // 524288
    int bh = idx >> 12, kv = idx & 4095, k = kv >> 6;
    float S = wkv_in[idx];
    for (int c = 0; c < 32; c++) {
        size_t off = (size_t)bh * 32 + c;
        float p = P[off * 4096 + kv];
        float a = aL[off * 64 + k];
        P[off * 4096 + kv] = S;   // Sb[c]
        S = S * a + p;
    }
    wkv_out[idx] = S;
}

__global__ __launch_bounds__(256) void wkv_y(
    const unsigned short* __restrict__ rr, const unsigned short* __restrict__ kd,
    const unsigned short* __restrict__ vv, const float* __restrict__ dec,
    const float* __restrict__ Sb, unsigned short* __restrict__ ya)
{
    __shared__ unsigned short rA[64][LP];
    __shared__ unsigned short kbL[64][LP];
    __shared__ unsigned short vT[64][LP];
    __shared__ unsigned short SbT[64][LP];
    __shared__ unsigned short QiM[64][LP];
    __shared__ float gp[4][64];
    const int blk = blockIdx.x;
    const int c = blk & 31, bh = blk >> 5, b = bh >> 5, h = bh & 31;
    const int tid = threadIdx.x;
    const size_t rowbase = ((size_t)(b * Tc + c * 64)) * Dc + h * 64;

    {
        int t = tid >> 2, q = tid & 3;
        const unsigned short* src = vv + rowbase + (size_t)t * Dc + q * 16;
        vushort8 a = *(const vushort8*)src;
        vushort8 b2 = *(const vushort8*)(src + 8);
#pragma unroll
        for (int j = 0; j < 8; j++) vT[q * 16 + j][t] = a[j];
#pragma unroll
        for (int j = 0; j < 8; j++) vT[q * 16 + 8 + j][t] = b2[j];
        const float* sp = Sb + (size_t)blk * 4096 + t * 64 + q * 16;
#pragma unroll
        for (int j = 0; j < 16; j++) SbT[q * 16 + j][t] = f2bf(sp[j]);
    }

    const int k = tid & 63, grp = tid >> 6;
    const float* decp = dec + rowbase + k;
    const unsigned short* rp = rr + rowbase + k;
    const unsigned short* kp = kd + rowbase + k;
    float pref_local[16];
    float pgrp = 1.f;
#pragma unroll
    for (int i = 0; i < 16; i++) {
        int t = grp * 16 + i;
        float d = decp[(size_t)t * Dc];
        pref_local[i] = pgrp;
        pgrp *= d;
    }
    gp[grp][k] = pgrp;
    __syncthreads();
    float pref = 1.f;
#pragma unroll
    for (int g2 = 0; g2 < 4; g2++) if (g2 < grp) pref *= gp[g2][k];
#pragma unroll
    for (int i = 0; i < 16; i++) {
        int t = grp * 16 + i;
        float Aex  = pref * pref_local[i];
        float Ainc = pref * (i < 15 ? pref_local[i + 1] : pgrp);
        rA[t][k]  = f2bf(bf2f(rp[(size_t)t * Dc]) * Aex);
        kbL[t][k] = f2bf(bf2f(kp[(size_t)t * Dc]) / Ainc);
    }
    __syncthreads();

    const int lane = tid & 63, w = tid >> 6;
    const int wm = (w >> 1) * 32, wn = (w & 1) * 32;
    const int frow = lane & 15, fk = (lane >> 4) * 8;

    vfloat4 acc[2][2];
#pragma unroll
    for (int m = 0; m < 2; m++)
#pragma unroll
        for (int n = 0; n < 2; n++) acc[m][n] = vfloat4{0.f, 0.f, 0.f, 0.f};
#pragma unroll
    for (int kk = 0; kk < 2; kk++) {
        vshort8 af[2], bfr[2];
#pragma unroll
        for (int m = 0; m < 2; m++) af[m]  = *(const vshort8*)&rA[wm + m * 16 + frow][kk * 32 + fk];
#pragma unroll
        for (int n = 0; n < 2; n++) bfr[n] = *(const vshort8*)&kbL[wn + n * 16 + frow][kk * 32 + fk];
#pragma unroll
        for (int m = 0; m < 2; m++)
#pragma unroll
            for (int n = 0; n < 2; n++)
                acc[m][n] = __builtin_amdgcn_mfma_f32_16x16x32_bf16(af[m], bfr[n], acc[m][n], 0, 0, 0);
    }
#pragma unroll
    for (int m = 0; m < 2; m++)
#pragma unroll
        for (int n = 0; n < 2; n++) {
            int s = wn + n * 16 + (lane & 15);
#pragma unroll
            for (int q = 0; q < 4; q++) {
                int t = wm + m * 16 + (lane >> 4) * 4 + q;
                QiM[t][s] = f2bf(s < t ? acc[m][n][q] : 0.f);
            }
        }
    __syncthreads();

#pragma unroll
    for (int m = 0; m < 2; m++)
#pragma unroll
        for (int n = 0; n < 2; n++) acc[m][n] = vfloat4{0.f, 0.f, 0.f, 0.f};
#pragma unroll
    for (int kk = 0; kk < 2; kk++) {
        vshort8 af[2], bfr[2];
#pragma unroll
        for (int m = 0; m < 2; m++) af[m]  = *(const vshort8*)&QiM[wm + m * 16 + frow][kk * 32 + fk];
#pragma unroll
        for (int n = 0; n < 2; n++) bfr[n] = *(const vshort8*)&vT[wn + n * 16 + frow][kk * 32 + fk];
#pragma unroll
        for (int m = 0; m < 2; m++)
#pragma unroll
            for (int n = 0; n < 2; n++)
                acc[m][n] = __builtin_amdgcn_mfma_f32_16x16x32_bf16(af[m], bfr[n], acc[m][n], 0, 0, 0);
    }
#pragma unroll
    for (int kk = 0; kk < 2; kk++) {
        vshort8 af[2], bfr[2];
#pragma unroll
        for (int m = 0; m < 2; m++) af[m]  = *(const vshort8*)&rA[wm + m * 16 + frow][kk * 32 + fk];
#pragma unroll
        for (int n = 0; n < 2; n++) bfr[n] = *(const vshort8*)&SbT[wn + n * 16 + frow][kk * 32 + fk];
#pragma unroll
        for (int m = 0; m < 2; m++)
#pragma unroll
            for (int n = 0; n < 2; n++)
                acc[m][n] = __builtin_amdgcn_mfma_f32_16x16x32_bf16(af[m], bfr[n], acc[m][n], 0, 0, 0);
    }
#pragma unroll
    for (int m = 0; m < 2; m++)
#pragma unroll
        for (int n = 0; n < 2; n++) {
            int col = wn + n * 16 + (lane & 15);
#pragma unroll
            for (int q = 0; q < 4; q++) {
                int t = wm + m * 16 + (lane >> 4) * 4 + q;
                ya[rowbase + (size_t)t * Dc + col] = f2bf(acc[m][n][q]);
            }
        }
}

// ---------------- LayerNorm(ya + v2) -> bf16 ----------------
__global__ __launch_bounds__(256) void ln_fuse(
    const unsigned short* __restrict__ ya, const unsigned short* __restrict__ v2,
    const float* __restrict__ lnw, const float* __restrict__ lnb,
    unsigned short* __restrict__ out)
{
    int row = blockIdx.x, tid = threadIdx.x;
    size_t base = (size_t)row * Dc + tid * 8;
    vushort8 a = *(const vushort8*)(ya + base);
    vushort8 b = *(const vushort8*)(v2 + base);
    float v[8]; float s = 0.f, s2 = 0.f;
#pragma unroll
    for (int j = 0; j < 8; j++) { float t = bf2f(a[j]) + bf2f(b[j]); v[j] = t; s += t; s2 += t * t; }
#pragma unroll
    for (int o = 32; o; o >>= 1) { s += __shfl_xor(s, o); s2 += __shfl_xor(s2, o); }
    __shared__ float rs[8];
    int w = tid >> 6;
    if ((tid & 63) == 0) { rs[w] = s; rs[w + 4] = s2; }
    __syncthreads();
    s  = rs[0] + rs[1] + rs[2] + rs[3];
    s2 = rs[4] + rs[5] + rs[6] + rs[7];
    float mu = s * (1.f / Dc);
    float var = s2 * (1.f / Dc) - mu * mu;
    float inv = rsqrtf(var + 1e-5f);
#pragma unroll
    for (int j = 0; j < 8; j++) {
        int d = tid * 8 + j;
        out[base + j] = f2bf((v[j] - mu) * inv * lnw[d] + lnb[d]);
    }
}

// ---------------- host ----------------
static inline void launch_gemm(int epi, const unsigned short* A, int lda,
                               const unsigned short* BT, int ldbt,
                               int M, int N, int K, EpiP ep, hipStream_t s)
{
    if ((M & 255) == 0 && (N & 255) == 0 && (K & 31) == 0) {
        dim3 g(N / 256, M / 256), b(512);
        switch (epi) {
            case 0: gemm256<0><<<g, b, 0, s>>>(A, lda, BT, ldbt, M, N, K, ep); break;
            case 1: gemm256<1><<<g, b, 0, s>>>(A, lda, BT, ldbt, M, N, K, ep); break;
            case 2: gemm256<2><<<g, b, 0, s>>>(A, lda, BT, ldbt, M, N, K, ep); break;
            case 3: gemm256<3><<<g, b, 0, s>>>(A, lda, BT, ldbt, M, N, K, ep); break;
            case 4: gemm256<4><<<g, b, 0, s>>>(A, lda, BT, ldbt, M, N, K, ep); break;
            case 5: gemm256<5><<<g, b, 0, s>>>(A, lda, BT, ldbt, M, N, K, ep); break;
            case 6: gemm256<6><<<g, b, 0, s>>>(A, lda, BT, ldbt, M, N, K, ep); break;
        }
        return;
    }
    dim3 g((N + 127) / 128, M / 128), b(256);
    switch (epi) {
        case 0: gemm_bt<0><<<g, b, 0, s>>>(A, lda, BT, ldbt, M, N, K, ep); break;
        case 1: gemm_bt<1><<<g, b, 0, s>>>(A, lda, BT, ldbt, M, N, K, ep); break;
        case 2: gemm_bt<2><<<g, b, 0, s>>>(A, lda, BT, ldbt, M, N, K, ep); break;
        case 3: gemm_bt<3><<<g, b, 0, s>>>(A, lda, BT, ldbt, M, N, K, ep); break;
        case 4: gemm_bt<4><<<g, b, 0, s>>>(A, lda, BT, ldbt, M, N, K, ep); break;
        case 5: gemm_bt<5><<<g, b, 0, s>>>(A, lda, BT, ldbt, M, N, K, ep); break;
        case 6: gemm_bt<6><<<g, b, 0, s>>>(A, lda, BT, ldbt, M, N, K, ep); break;
    }
}

extern "C" void kernel_launch(void* const* d_in, const int* in_sizes, int n_in,
                              void* d_out, int out_size, void* d_ws, size_t ws_size,
                              hipStream_t stream)
{
    (void)in_sizes; (void)n_in; (void)out_size; (void)ws_size;
    const float* x      = (const float*)d_in[0];
    const float* shift  = (const float*)d_in[1];
    const float* wkv_in = (const float*)d_in[2];
    const float* tmx    = (const float*)d_in[3];
    const float* tmr    = (const float*)d_in[4];
    const float* tmk    = (const float*)d_in[5];
    const float* tmv    = (const float*)d_in[6];
    const float* tmw    = (const float*)d_in[7];
    const float* tmv2   = (const float*)d_in[8];
    const float* w1     = (const float*)d_in[9];
    const float* w2     = (const float*)d_in[10];
    const float* tdecay = (const float*)d_in[11];
    const float* tdw1   = (const float*)d_in[12];
    const float* tdw2   = (const float*)d_in[13];
    const float* tv2w1  = (const float*)d_in[14];
    const float* tv2w2  = (const float*)d_in[15];
    const float* Wr     = (const float*)d_in[16];
    const float* Wk     = (const float*)d_in[17];
    const float* Wv     = (const float*)d_in[18];
    const float* Wo     = (const float*)d_in[19];
    const float* lnw    = (const float*)d_in[20];
    const float* lnb    = (const float*)d_in[21];

    // ---- workspace layout (lifetimes aliased) ----
    char* ws = (char*)d_ws;
    const size_t BF = 2 * BTDc;
    size_t o = 0;
    auto take = [&](size_t bytes) { size_t r = o; o += (bytes + 255) & ~(size_t)255; return r; };
    unsigned short* WrT    = (unsigned short*)(ws + take((size_t)Dc * Dc * 2));
    unsigned short* WkT    = (unsigned short*)(ws + take((size_t)Dc * Dc * 2));
    unsigned short* WvT    = (unsigned short*)(ws + take((size_t)Dc * Dc * 2));
    unsigned short* WoT    = (unsigned short*)(ws + take((size_t)Dc * Dc * 2));
    unsigned short* w1T    = (unsigned short*)(ws + take((size_t)160 * Dc * 2));
    unsigned short* w2T    = (unsigned short*)(ws + take((size_t)Dc * 160 * 2));
    unsigned short* tdw1T  = (unsigned short*)(ws + take((size_t)64 * Dc * 2));
    unsigned short* tdw2T  = (unsigned short*)(ws + take((size_t)Dc * 64 * 2));
    unsigned short* tv2w1T = (unsigned short*)(ws + take((size_t)64 * Dc * 2));
    unsigned short* tv2w2T = (unsigned short*)(ws + take((size_t)Dc * 64 * 2));
    take(1 << 18);
    unsigned short* BUF0   = (unsigned short*)(ws + take(BF));                  // XXX -> Rb/XV2
    unsigned short* MIXPRE = (unsigned short*)(ws + take((size_t)BTc * 160 * 2));
    unsigned short* BUF1   = (unsigned short*)(ws + take(BF));                  // XM -> YA
    unsigned short* WT     = (unsigned short*)(ws + take((size_t)BTc * 64 * 2));
    unsigned short* T1     = (unsigned short*)(ws + take((size_t)BTc * 64 * 2));
    unsigned short* BUF2   = (unsigned short*)(ws + take(BF));                  // KDb -> V2
    unsigned short* BUF3   = (unsigned short*)(ws + take(BF));                  // Vb -> YLN
    float*          Pb     = (float*)(ws + take((size_t)128 * 32 * 4096 * 4));
    float*          ALb    = (float*)(ws + take((size_t)128 * 32 * 64 * 4));

    float* out_f     = (float*)d_out;
    float* shift_out = out_f + BTDc;
    float* wkv_out   = shift_out + (size_t)Bc * Dc;
    float* DEC       = out_f;

    unsigned short* XXX = BUF0;
    unsigned short* Rb  = BUF0;
    unsigned short* XV2 = BUF0;
    unsigned short* XM  = BUF1;
    unsigned short* YA  = BUF1;
    unsigned short* KDb = BUF2;
    unsigned short* V2  = BUF2;
    unsigned short* Vb  = BUF3;
    unsigned short* YLN = BUF3;

    dim3 tb(256);
    transpose_cast<<<dim3(64, 64), tb, 0, stream>>>(Wr, WrT, Dc, Dc);
    transpose_cast<<<dim3(64, 64), tb, 0, stream>>>(Wk, WkT, Dc, Dc);
    transpose_cast<<<dim3(64, 64), tb, 0, stream>>>(Wv, WvT, Dc, Dc);
    transpose_cast<<<dim3(64, 64), tb, 0, stream>>>(Wo, WoT, Dc, Dc);
    transpose_cast<<<dim3(5, 64),  tb, 0, stream>>>(w1, w1T, Dc, 160);
    transpose_cast<<<dim3(64, 5),  tb, 0, stream>>>(w2, w2T, 160, Dc);
    transpose_cast<<<dim3(2, 64),  tb, 0, stream>>>(tdw1, tdw1T, Dc, 64);
    transpose_cast<<<dim3(64, 2),  tb, 0, stream>>>(tdw2, tdw2T, 64, Dc);
    transpose_cast<<<dim3(2, 64),  tb, 0, stream>>>(tv2w1, tv2w1T, Dc, 64);
    transpose_cast<<<dim3(64, 2),  tb, 0, stream>>>(tv2w2, tv2w2T, 64, Dc);

    prep_xxx<<<BTc, tb, 0, stream>>>(x, shift, tmx, XXX);
    shift_copy<<<32, tb, 0, stream>>>(x, shift_out);

    EpiP ep{};
    ep = EpiP{}; ep.ob = MIXPRE;
    launch_gemm(2, XXX, Dc, w1T, Dc, BTc, 160, Dc, ep, stream);

    const float* tmaa[5] = {tmr, tmk, tmv, tmw, tmv2};
    auto mix_into = [&](int f, unsigned short* dst) {
        EpiP e{}; e.ob = dst; e.a0 = x; e.a1 = shift; e.vec = tmaa[f];
        launch_gemm(3, MIXPRE + f * 32, 160, w2T + f * 32, 160, BTc, Dc, 32, e, stream);
    };

    // decay path
    mix_into(3, XM);
    ep = EpiP{}; ep.ob = WT;
    launch_gemm(2, XM, Dc, tdw1T, Dc, BTc, 64, Dc, ep, stream);
    ep = EpiP{}; ep.of = DEC; ep.vec = tdecay;
    launch_gemm(5, WT, 64, tdw2T, 64, BTc, Dc, 64, ep, stream);
    // k*(1-decay)
    mix_into(1, XM);
    ep = EpiP{}; ep.ob = KDb; ep.a0 = DEC;
    launch_gemm(4, XM, Dc, WkT, Dc, BTc, Dc, Dc, ep, stream);
    // v
    mix_into(2, XM);
    ep = EpiP{}; ep.ob = Vb;
    launch_gemm(1, XM, Dc, WvT, Dc, BTc, Dc, Dc, ep, stream);
    // r
    mix_into(0, XM);
    ep = EpiP{}; ep.ob = Rb;
    launch_gemm(1, XM, Dc, WrT, Dc, BTc, Dc, Dc, ep, stream);

    // chunked WKV scan (MFMA)
    wkv_summary<<<4096, tb, 0, stream>>>(KDb, Vb, DEC, Pb, ALb);
    wkv_states<<<2048, tb, 0, stream>>>(wkv_in, Pb, ALb, wkv_out);
    wkv_y<<<4096, tb, 0, stream>>>(Rb, KDb, Vb, DEC, Pb, YA);

    // v2 path (into dead buffers)
    mix_into(4, XV2);
    ep = EpiP{}; ep.ob = V2;
    launch_gemm(1, XV2, Dc, WvT, Dc, BTc, Dc, Dc, ep, stream);
    ep = EpiP{}; ep.ob = T1;
    launch_gemm(2, XV2, Dc, tv2w1T, Dc, BTc, 64, Dc, ep, stream);
    ep = EpiP{}; ep.ob = V2; ep.ab = V2;
    launch_gemm(6, T1, 64, tv2w2T, 64, BTc, Dc, 64, ep, stream);

    // layernorm + output projection
    ln_fuse<<<BTc, tb, 0, stream>>>(YA, V2, lnw, lnb, YLN);
    ep = EpiP{}; ep.of = out_f;
    launch_gemm(0, YLN, Dc, WoT, Dc, BTc, Dc, Dc, ep, stream);
}